// Round 2
// baseline (292.780 us; speedup 1.0000x reference)
//
#include <hip/hip_runtime.h>

#define N_NODES 100000
#define N_EDGES 1600000
#define D 64
#define SCAN_BLOCK 1024
#define N_CHUNKS 98          // 98*1024 = 100352 >= N_NODES
#define NCOPY 8
#define CSTRIDE 100352       // per-copy counter stride (ints)
#define HIST_SPAN_SHIFT 10   // each hist/fill block spans 1024 edges

// ---- ws layout (4-byte units), total ~20 MB (ws >= 20,400,640 B) ----
#define WS_CNT      0                      // [NCOPY*CSTRIDE] counts -> absolute bases
#define WS_TOTAL    (NCOPY*CSTRIDE)        // [100000] node degree
#define WS_ROWPTR   (WS_TOTAL + 100000)    // [100001] (+pad)
#define WS_PARTIAL  (WS_ROWPTR + 100032)   // [128]
#define WS_RANK     (WS_PARTIAL + 128)     // ushort[1600000] = 800000 ints
#define WS_PAIRS    (WS_RANK + 800000)     // int2[1600000]

// ---------------- CSR build ----------------

// Privatized histogram (copy = blockIdx&7, aligned with the 1024-edge span so
// fill can recompute it from e>>10). Vectorized: int4 src load, 4 atomic
// returns in flight, ushort4 rank store.
__global__ __launch_bounds__(256) void k_hist_rank(
    const int* __restrict__ esrc, int* __restrict__ cnt,
    unsigned short* __restrict__ rank)
{
    int* mycnt = cnt + (blockIdx.x & (NCOPY - 1)) * CSTRIDE;
    int e0 = blockIdx.x * 1024 + threadIdx.x * 4;
    if (e0 >= N_EDGES) return;           // N_EDGES % 4 == 0 -> whole int4 valid
    int4 s4 = *(const int4*)(esrc + e0);
    int r0 = atomicAdd(&mycnt[s4.x], 1);
    int r1 = atomicAdd(&mycnt[s4.y], 1);
    int r2 = atomicAdd(&mycnt[s4.z], 1);
    int r3 = atomicAdd(&mycnt[s4.w], 1);
    ushort4 rr;
    rr.x = (unsigned short)r0; rr.y = (unsigned short)r1;
    rr.z = (unsigned short)r2; rr.w = (unsigned short)r3;
    *(ushort4*)(rank + e0) = rr;
}

// Per node: exclusive scan over the 8 copy-counts (written back in place),
// node total, per-chunk partial sums.
__global__ __launch_bounds__(SCAN_BLOCK) void k_copy_scan(
    int* __restrict__ cnt, int* __restrict__ total, int* __restrict__ partial)
{
    __shared__ int sred[16];
    int t = threadIdx.x;
    int i = blockIdx.x * SCAN_BLOCK + t;
    int tot = 0;
    if (i < N_NODES) {
        int c[NCOPY];
        #pragma unroll
        for (int k = 0; k < NCOPY; ++k) c[k] = cnt[k * CSTRIDE + i];
        int run = 0;
        #pragma unroll
        for (int k = 0; k < NCOPY; ++k) {
            cnt[k * CSTRIDE + i] = run;
            run += c[k];
        }
        tot = run;
        total[i] = run;
    }
    int v = tot;
    #pragma unroll
    for (int off = 32; off; off >>= 1) v += __shfl_down(v, off, 64);
    if ((t & 63) == 0) sred[t >> 6] = v;
    __syncthreads();
    if (t < 16) {
        int w = sred[t];
        #pragma unroll
        for (int off = 8; off; off >>= 1) w += __shfl_down(w, off, 16);
        if (t == 0) partial[blockIdx.x] = w;
    }
}

// row_ptr[i] = global exclusive scan of degree; folds row_ptr into the 8
// per-copy bases. The 98-entry partial scan is done redundantly per block
// (no separate k_scan_partial launch).
__global__ __launch_bounds__(SCAN_BLOCK) void k_chunk_scan(
    const int* __restrict__ total, const int* __restrict__ partial,
    int* __restrict__ row_ptr, int* __restrict__ bases)
{
    __shared__ int wsum[16];
    __shared__ int red1[16], red2[16];
    __shared__ int bc[2];                 // [0]=chunk base, [1]=grand total
    int t = threadIdx.x;
    int lane = t & 63, wid = t >> 6;

    // --- reduce raw partials: base for this chunk (t < blockIdx) + grand ---
    int pv = (t < N_CHUNKS) ? partial[t] : 0;
    int a1 = (t < (int)blockIdx.x) ? pv : 0;
    int a2 = pv;
    #pragma unroll
    for (int off = 32; off; off >>= 1) {
        a1 += __shfl_down(a1, off, 64);
        a2 += __shfl_down(a2, off, 64);
    }
    if (lane == 0) { red1[wid] = a1; red2[wid] = a2; }
    __syncthreads();
    if (t < 16) {
        int w1 = red1[t], w2 = red2[t];
        #pragma unroll
        for (int off = 8; off; off >>= 1) {
            w1 += __shfl_down(w1, off, 16);
            w2 += __shfl_down(w2, off, 16);
        }
        if (t == 0) { bc[0] = w1; bc[1] = w2; }
    }
    __syncthreads();

    // --- per-chunk exclusive scan of node totals ---
    int i = blockIdx.x * SCAN_BLOCK + t;
    int v = (i < N_NODES) ? total[i] : 0;
    int s = v;
    #pragma unroll
    for (int off = 1; off < 64; off <<= 1) {
        int y = __shfl_up(s, off, 64);
        if (lane >= off) s += y;
    }
    if (lane == 63) wsum[wid] = s;
    __syncthreads();
    if (t < 16) {
        int w = wsum[t];
        #pragma unroll
        for (int off = 1; off < 16; off <<= 1) {
            int y = __shfl_up(w, off, 16);
            if (t >= off) w += y;
        }
        wsum[t] = w;
    }
    __syncthreads();
    int prefix = wid ? wsum[wid - 1] : 0;
    if (i < N_NODES) {
        int rp = bc[0] + prefix + s - v;
        row_ptr[i] = rp;
        #pragma unroll
        for (int k = 0; k < NCOPY; ++k) bases[k * CSTRIDE + i] += rp;
    }
    if (blockIdx.x == N_CHUNKS - 1 && t == 0) row_ptr[N_NODES] = bc[1];
}

// pos = bases[copy][src] + rank ; copy recomputed from edge index.
__global__ __launch_bounds__(256) void k_fill_rank(
    const int* __restrict__ esrc, const int* __restrict__ edst,
    const float* __restrict__ eval_, const int* __restrict__ bases,
    const unsigned short* __restrict__ rank, int2* __restrict__ pairs)
{
    int e0 = blockIdx.x * 1024 + threadIdx.x * 4;
    if (e0 >= N_EDGES) return;
    int4 s4 = *(const int4*)(esrc + e0);
    int4 d4 = *(const int4*)(edst + e0);
    float4 v4 = *(const float4*)(eval_ + e0);
    ushort4 r4 = *(const ushort4*)(rank + e0);
    const int* b = bases + ((e0 >> HIST_SPAN_SHIFT) & (NCOPY - 1)) * CSTRIDE;
    int p0 = b[s4.x] + (int)r4.x;
    int p1 = b[s4.y] + (int)r4.y;
    int p2 = b[s4.z] + (int)r4.z;
    int p3 = b[s4.w] + (int)r4.w;
    pairs[p0] = make_int2(d4.x, __float_as_int(v4.x));
    pairs[p1] = make_int2(d4.y, __float_as_int(v4.y));
    pairs[p2] = make_int2(d4.z, __float_as_int(v4.z));
    pairs[p3] = make_int2(d4.w, __float_as_int(v4.w));
}

// ---------------- fused aggregation + GEMM ----------------
// rep = agg + eps*x ; out = rep @ W + bias, fused into the gather epilogue.
// Rationale (R1 post-mortem): gather is pinned at ~67us by the L2-miss
// service rate (identical time across two structures, ~3.3 TB/s); its VALU is
// ~80% idle, so the 64x64 GEMM hides under the miss stalls and we delete
// k_gemm's 25.6MB rep re-read + dispatch entirely.
// Layout: 4 edges x 16 lanes per wave, lane loads float4 (1KB/instr).
// After the xor-16/32 butterfly ALL lanes hold the reduced chunk (lane&15);
// repv = acc + eps*x chunk is 4-way replicated; __shfl from lanes 0..15
// broadcasts the full 64-float rep row; each lane owns one output column
// (W column in 64 VGPRs), coalesced dword store.
#define GATHER_BLOCKS 2048

__global__ __launch_bounds__(256, 4) void k_gather_gemm(
    const float* __restrict__ x, const int* __restrict__ row_ptr,
    const int2* __restrict__ pairs, const float* __restrict__ epsilon,
    const float* __restrict__ weight, const float* __restrict__ bias,
    float* __restrict__ rep, float* __restrict__ out)
{
    int w = (blockIdx.x * 256 + threadIdx.x) >> 6;   // global wave id
    int nw = gridDim.x * 4;                          // 8192
    int lane = threadIdx.x & 63;
    int sub = lane >> 4;                             // edge slot 0..3
    int f4 = lane & 15;                              // float4 index in row
    float eps = epsilon[0];
    const float4* x4 = (const float4*)x;

    // W column for this lane: wcol[k] = W[k][lane]; coalesced across lanes.
    float wcol[D];
    #pragma unroll
    for (int k = 0; k < D; ++k) wcol[k] = weight[k * D + lane];
    float bl = bias[lane];

    int r0 = (int)((long long)w * N_NODES / nw);
    int r1 = (int)((long long)(w + 1) * N_NODES / nw);

    for (int row = r0; row < r1; ++row) {
        int start = __builtin_amdgcn_readfirstlane(row_ptr[row]);
        int end   = __builtin_amdgcn_readfirstlane(row_ptr[row + 1]);
        float4 acc = make_float4(0.f, 0.f, 0.f, 0.f);
        for (int j = start; j < end; j += 16) {
            int2 p[4];
            #pragma unroll
            for (int u = 0; u < 4; ++u) {
                int e = j + u * 4 + sub;
                p[u] = (e < end) ? pairs[e] : make_int2(0, 0);
            }
            float4 a[4];
            #pragma unroll
            for (int u = 0; u < 4; ++u)
                a[u] = x4[(size_t)p[u].x * 16 + f4];   // row 0 if masked; val=0
            #pragma unroll
            for (int u = 0; u < 4; ++u) {
                float vv = __int_as_float(p[u].y);
                acc.x += vv * a[u].x; acc.y += vv * a[u].y;
                acc.z += vv * a[u].z; acc.w += vv * a[u].w;
            }
        }
        // butterfly: every lane gets the sum over the 4 edge-slots
        #pragma unroll
        for (int off = 16; off <= 32; off <<= 1) {
            acc.x += __shfl_xor(acc.x, off, 64);
            acc.y += __shfl_xor(acc.y, off, 64);
            acc.z += __shfl_xor(acc.z, off, 64);
            acc.w += __shfl_xor(acc.w, off, 64);
        }
        // rep chunk (4-way replicated across subs)
        float4 xv = x4[(size_t)row * 16 + f4];
        float4 repv = make_float4(acc.x + eps * xv.x, acc.y + eps * xv.y,
                                  acc.z + eps * xv.z, acc.w + eps * xv.w);
        if (sub == 0)
            ((float4*)rep)[(size_t)row * 16 + f4] = repv;

        // out[row][lane] = sum_k rep[k] * W[k][lane] + bias[lane]
        // rep chunk j lives (replicated) in lane j (j<16).
        float o = bl;
        #pragma unroll
        for (int j = 0; j < 16; ++j) {
            float rx = __shfl(repv.x, j, 64);
            float ry = __shfl(repv.y, j, 64);
            float rz = __shfl(repv.z, j, 64);
            float rw = __shfl(repv.w, j, 64);
            o += rx * wcol[4 * j + 0] + ry * wcol[4 * j + 1]
               + rz * wcol[4 * j + 2] + rw * wcol[4 * j + 3];
        }
        out[(size_t)row * D + lane] = o;
    }
}

extern "C" void kernel_launch(void* const* d_in, const int* in_sizes, int n_in,
                              void* d_out, int out_size, void* d_ws, size_t ws_size,
                              hipStream_t stream) {
    const float* x    = (const float*)d_in[0];
    const int*   esrc = (const int*)  d_in[1];
    const int*   edst = (const int*)  d_in[2];
    const float* ev   = (const float*)d_in[3];
    const float* w    = (const float*)d_in[4];
    const float* eps  = (const float*)d_in[5];
    const float* bias = (const float*)d_in[6];

    float* out = (float*)d_out;
    float* rep = out + (size_t)N_NODES * D;

    int* ws      = (int*)d_ws;
    int* cnt     = ws + WS_CNT;
    int* total   = ws + WS_TOTAL;
    int* row_ptr = ws + WS_ROWPTR;
    int* partial = ws + WS_PARTIAL;
    unsigned short* rank = (unsigned short*)(ws + WS_RANK);
    int2* pairs  = (int2*)(ws + WS_PAIRS);

    hipMemsetAsync(cnt, 0, (size_t)NCOPY * CSTRIDE * sizeof(int), stream);

    int egrid = (N_EDGES + 1023) / 1024;   // 1563 blocks, 1024 edges each
    k_hist_rank<<<egrid, 256, 0, stream>>>(esrc, cnt, rank);
    k_copy_scan<<<N_CHUNKS, SCAN_BLOCK, 0, stream>>>(cnt, total, partial);
    k_chunk_scan<<<N_CHUNKS, SCAN_BLOCK, 0, stream>>>(total, partial, row_ptr, cnt);
    k_fill_rank<<<egrid, 256, 0, stream>>>(esrc, edst, ev, cnt, rank, pairs);
    k_gather_gemm<<<GATHER_BLOCKS, 256, 0, stream>>>(x, row_ptr, pairs, eps,
                                                     w, bias, rep, out);
}

// Round 3
// 236.488 us; speedup vs baseline: 1.2380x; 1.2380x over previous
//
#include <hip/hip_runtime.h>

#define N_NODES 100000
#define N_EDGES 1600000
#define D 64

// ---------- counting-sort CSR build parameters ----------
#define NB 391            // buckets = src>>8 (100000>>8 = 390)
#define BLKA 196          // pass-A blocks
#define EPB 8192          // edges per pass-A block (256 thr x 8 x int4)
#define NT (NB * BLKA)    // 76636 ghist entries
#define NCH 75            // ceil(NT/1024) scan chunks

// ---- ws layout (4-byte units), total ~19.9 MB (proven ws >= 20,400,640 B) ----
#define WS_GHIST   0                       // [NT] per-(bucket,block) counts -> scanned bases
#define WS_PART    76672                   // [128] chunk partials
#define WS_ROWPTR  76800                   // [100001] (+pad)
#define WS_KEYS    176832                  // int[1600000] bucket-sorted src
#define WS_PAIRS   1776832                 // int2[1600000] final CSR payload
// tpairs (int2[1600000], bucket-sorted payload) lives in the rep region of
// d_out: it is fully consumed by k_build_csr before k_gather writes rep.

// ---------------- pass A: per-(bucket,block) histogram ----------------
__global__ __launch_bounds__(256) void k_bucket_hist(
    const int* __restrict__ esrc, int* __restrict__ ghist)
{
    __shared__ int h[NB];
    int t = threadIdx.x;
    for (int j = t; j < NB; j += 256) h[j] = 0;
    __syncthreads();
    int base = blockIdx.x * EPB;
    #pragma unroll
    for (int i = 0; i < 8; ++i) {
        int e0 = base + i * 1024 + t * 4;
        if (e0 < N_EDGES) {                  // N_EDGES%4==0 -> whole int4 valid
            int4 s4 = *(const int4*)(esrc + e0);
            atomicAdd(&h[s4.x >> 8], 1);
            atomicAdd(&h[s4.y >> 8], 1);
            atomicAdd(&h[s4.z >> 8], 1);
            atomicAdd(&h[s4.w >> 8], 1);
        }
    }
    __syncthreads();
    // flattened bucket-major layout: ghist[j*BLKA + blk]
    for (int j = t; j < NB; j += 256) ghist[j * BLKA + blockIdx.x] = h[j];
}

// ---------------- scan of ghist (2-kernel redundant-partial pattern) ----------------
__global__ __launch_bounds__(1024) void k_ghist_scan1(
    const int* __restrict__ ghist, int* __restrict__ partial)
{
    __shared__ int sred[16];
    int t = threadIdx.x;
    int idx = blockIdx.x * 1024 + t;
    int v = (idx < NT) ? ghist[idx] : 0;
    #pragma unroll
    for (int off = 32; off; off >>= 1) v += __shfl_down(v, off, 64);
    if ((t & 63) == 0) sred[t >> 6] = v;
    __syncthreads();
    if (t < 16) {
        int w = sred[t];
        #pragma unroll
        for (int off = 8; off; off >>= 1) w += __shfl_down(w, off, 16);
        if (t == 0) partial[blockIdx.x] = w;
    }
}

__global__ __launch_bounds__(1024) void k_ghist_scan2(
    int* __restrict__ ghist, const int* __restrict__ partial)
{
    __shared__ int red1[16];
    __shared__ int wsum[16];
    __shared__ int bc;
    int t = threadIdx.x;
    int lane = t & 63, wid = t >> 6;

    // base = sum of partials of chunks before this one (redundant per block)
    int pv = (t < NCH) ? partial[t] : 0;
    int a1 = (t < (int)blockIdx.x) ? pv : 0;
    #pragma unroll
    for (int off = 32; off; off >>= 1) a1 += __shfl_down(a1, off, 64);
    if (lane == 0) red1[wid] = a1;
    __syncthreads();
    if (t < 16) {
        int w = red1[t];
        #pragma unroll
        for (int off = 8; off; off >>= 1) w += __shfl_down(w, off, 16);
        if (t == 0) bc = w;
    }
    __syncthreads();

    // exclusive scan of this chunk, in place
    int idx = blockIdx.x * 1024 + t;
    int v = (idx < NT) ? ghist[idx] : 0;
    int s = v;
    #pragma unroll
    for (int off = 1; off < 64; off <<= 1) {
        int y = __shfl_up(s, off, 64);
        if (lane >= off) s += y;
    }
    if (lane == 63) wsum[wid] = s;
    __syncthreads();
    if (t < 16) {
        int w = wsum[t];
        #pragma unroll
        for (int off = 1; off < 16; off <<= 1) {
            int y = __shfl_up(w, off, 16);
            if (t >= off) w += y;
        }
        wsum[t] = w;
    }
    __syncthreads();
    int prefix = wid ? wsum[wid - 1] : 0;
    if (idx < NT) ghist[idx] = bc + prefix + s - v;
}

// ---------------- pass A scatter: bucket-partition edges ----------------
// Each (bucket, block) owns a contiguous output range (from scanned ghist);
// LDS atomic-returns generate ranks, writes are 391 sequential windows.
__global__ __launch_bounds__(256) void k_scatter(
    const int* __restrict__ esrc, const int* __restrict__ edst,
    const float* __restrict__ eval_, const int* __restrict__ ghist,
    int* __restrict__ keys, int2* __restrict__ tpairs)
{
    __shared__ int base[NB];
    int t = threadIdx.x;
    for (int j = t; j < NB; j += 256) base[j] = ghist[j * BLKA + blockIdx.x];
    __syncthreads();
    int eb = blockIdx.x * EPB;
    #pragma unroll
    for (int i = 0; i < 8; ++i) {
        int e0 = eb + i * 1024 + t * 4;
        if (e0 < N_EDGES) {
            int4 s4 = *(const int4*)(esrc + e0);
            int4 d4 = *(const int4*)(edst + e0);
            float4 v4 = *(const float4*)(eval_ + e0);
            int p0 = atomicAdd(&base[s4.x >> 8], 1);
            int p1 = atomicAdd(&base[s4.y >> 8], 1);
            int p2 = atomicAdd(&base[s4.z >> 8], 1);
            int p3 = atomicAdd(&base[s4.w >> 8], 1);
            keys[p0] = s4.x; tpairs[p0] = make_int2(d4.x, __float_as_int(v4.x));
            keys[p1] = s4.y; tpairs[p1] = make_int2(d4.y, __float_as_int(v4.y));
            keys[p2] = s4.z; tpairs[p2] = make_int2(d4.z, __float_as_int(v4.z));
            keys[p3] = s4.w; tpairs[p3] = make_int2(d4.w, __float_as_int(v4.w));
        }
    }
}

// ---------------- pass B: per-bucket CSR finalize ----------------
// One 256-thread block per bucket (256 nodes, ~4.1K edges): LDS 256-bin
// histogram + scan gives row_ptr AND in-bucket offsets; LDS atomic-returns
// rank; scatter lands in a ~32KB L2-resident window.
__global__ __launch_bounds__(256) void k_build_csr(
    const int* __restrict__ keys, const int2* __restrict__ tpairs,
    const int* __restrict__ ghist, int* __restrict__ row_ptr,
    int2* __restrict__ pairs)
{
    __shared__ int hist[256], cursor[256], wsum4[4];
    int b = blockIdx.x, t = threadIdx.x;
    int s_begin = ghist[b * BLKA];
    int s_end = (b + 1 < NB) ? ghist[(b + 1) * BLKA] : N_EDGES;
    hist[t] = 0;
    __syncthreads();
    #pragma unroll 4
    for (int pos = s_begin + t; pos < s_end; pos += 256)
        atomicAdd(&hist[keys[pos] & 255], 1);
    __syncthreads();
    // exclusive scan of 256 bins
    int lane = t & 63, wid = t >> 6;
    int v = hist[t], s = v;
    #pragma unroll
    for (int off = 1; off < 64; off <<= 1) {
        int y = __shfl_up(s, off, 64);
        if (lane >= off) s += y;
    }
    if (lane == 63) wsum4[wid] = s;
    __syncthreads();
    if (t == 0) {
        int r = 0;
        #pragma unroll
        for (int k = 0; k < 4; ++k) { int x = wsum4[k]; wsum4[k] = r; r += x; }
    }
    __syncthreads();
    int excl = wsum4[wid] + s - v;
    cursor[t] = excl;
    int node = (b << 8) + t;
    if (node <= N_NODES) row_ptr[node] = s_begin + excl;
    __syncthreads();
    #pragma unroll 4
    for (int pos = s_begin + t; pos < s_end; pos += 256) {
        int k = keys[pos] & 255;
        int2 pv = tpairs[pos];
        int p = atomicAdd(&cursor[k], 1);
        pairs[s_begin + p] = pv;
    }
}

// ---------------- aggregation: rep = agg + eps*x (R1-proven, 67us wall) ----------------
// 4 edges x 16 lanes per wave, lane loads float4 (1KB/VMEM-instr); single
// masked 16-edge step; grid 2048 blocks = 32 waves/CU. Pinned at the ~3.4TB/s
// L2-miss service rate — do NOT trade occupancy here (R2 fusion lesson).
#define GATHER_BLOCKS 2048

__global__ __launch_bounds__(256) void k_gather(
    const float* __restrict__ x, const int* __restrict__ row_ptr,
    const int2* __restrict__ pairs, const float* __restrict__ epsilon,
    float* __restrict__ rep)
{
    int w = (blockIdx.x * 256 + threadIdx.x) >> 6;   // global wave id
    int nw = gridDim.x * 4;                          // 8192
    int lane = threadIdx.x & 63;
    int sub = lane >> 4;                             // edge slot 0..3
    int f4 = lane & 15;                              // float4 index in row
    float eps = epsilon[0];
    const float4* x4 = (const float4*)x;

    int r0 = (int)((long long)w * N_NODES / nw);
    int r1 = (int)((long long)(w + 1) * N_NODES / nw);

    for (int row = r0; row < r1; ++row) {
        int start = __builtin_amdgcn_readfirstlane(row_ptr[row]);
        int end   = __builtin_amdgcn_readfirstlane(row_ptr[row + 1]);
        float4 acc = make_float4(0.f, 0.f, 0.f, 0.f);
        for (int j = start; j < end; j += 16) {
            int2 p[4];
            #pragma unroll
            for (int u = 0; u < 4; ++u) {
                int e = j + u * 4 + sub;
                p[u] = (e < end) ? pairs[e] : make_int2(0, 0);
            }
            float4 a[4];
            #pragma unroll
            for (int u = 0; u < 4; ++u)
                a[u] = x4[(size_t)p[u].x * 16 + f4];   // row 0 if masked; val=0
            #pragma unroll
            for (int u = 0; u < 4; ++u) {
                float vv = __int_as_float(p[u].y);
                acc.x += vv * a[u].x; acc.y += vv * a[u].y;
                acc.z += vv * a[u].z; acc.w += vv * a[u].w;
            }
        }
        #pragma unroll
        for (int off = 16; off <= 32; off <<= 1) {
            acc.x += __shfl_xor(acc.x, off, 64);
            acc.y += __shfl_xor(acc.y, off, 64);
            acc.z += __shfl_xor(acc.z, off, 64);
            acc.w += __shfl_xor(acc.w, off, 64);
        }
        if (sub == 0) {
            float4 xv = x4[(size_t)row * 16 + f4];
            float4 o = make_float4(acc.x + eps * xv.x, acc.y + eps * xv.y,
                                   acc.z + eps * xv.z, acc.w + eps * xv.w);
            ((float4*)rep)[(size_t)row * 16 + f4] = o;
        }
    }
}

// ---------------- out = rep @ W + bias ----------------
#define GEMM_TM 64
__global__ __launch_bounds__(256) void k_gemm(
    const float* __restrict__ rep, const float* __restrict__ weight,
    const float* __restrict__ bias, float* __restrict__ out)
{
    __shared__ float rep_s[GEMM_TM * 68];
    __shared__ float Ws[D * D];
    int t = threadIdx.x;
    {
        const float4* w4 = (const float4*)weight;
        float4* s4 = (float4*)Ws;
        #pragma unroll
        for (int i = 0; i < (D * D / 4) / 256; ++i)
            s4[t + i * 256] = w4[t + i * 256];
    }
    int row0 = blockIdx.x * GEMM_TM;
    {
        const float4* r4 = (const float4*)rep;
        #pragma unroll
        for (int i = 0; i < 4; ++i) {
            int f = t + i * 256;
            int rr = f >> 4, kk4 = f & 15;
            float4 v = (row0 + rr < N_NODES) ? r4[(size_t)(row0 + rr) * 16 + kk4]
                                             : make_float4(0.f, 0.f, 0.f, 0.f);
            rep_s[rr * 68 + kk4 * 4 + 0] = v.x;
            rep_s[rr * 68 + kk4 * 4 + 1] = v.y;
            rep_s[rr * 68 + kk4 * 4 + 2] = v.z;
            rep_s[rr * 68 + kk4 * 4 + 3] = v.w;
        }
    }
    __syncthreads();

    int tx = t & 15, ty = t >> 4;
    float4 b4 = ((const float4*)bias)[tx];
    float acc[4][4];
    #pragma unroll
    for (int i = 0; i < 4; ++i) {
        acc[i][0] = b4.x; acc[i][1] = b4.y; acc[i][2] = b4.z; acc[i][3] = b4.w;
    }
    #pragma unroll 4
    for (int k4 = 0; k4 < 16; ++k4) {
        float4 rv[4];
        #pragma unroll
        for (int i = 0; i < 4; ++i)
            rv[i] = *(const float4*)&rep_s[(ty * 4 + i) * 68 + k4 * 4];
        #pragma unroll
        for (int kk = 0; kk < 4; ++kk) {
            float4 wv = *(const float4*)&Ws[(k4 * 4 + kk) * D + tx * 4];
            #pragma unroll
            for (int i = 0; i < 4; ++i) {
                float r = ((const float*)&rv[i])[kk];
                acc[i][0] += r * wv.x;
                acc[i][1] += r * wv.y;
                acc[i][2] += r * wv.z;
                acc[i][3] += r * wv.w;
            }
        }
    }
    #pragma unroll
    for (int i = 0; i < 4; ++i) {
        int row = row0 + ty * 4 + i;
        if (row < N_NODES)
            *(float4*)&out[(size_t)row * D + tx * 4] =
                make_float4(acc[i][0], acc[i][1], acc[i][2], acc[i][3]);
    }
}

extern "C" void kernel_launch(void* const* d_in, const int* in_sizes, int n_in,
                              void* d_out, int out_size, void* d_ws, size_t ws_size,
                              hipStream_t stream) {
    const float* x    = (const float*)d_in[0];
    const int*   esrc = (const int*)  d_in[1];
    const int*   edst = (const int*)  d_in[2];
    const float* ev   = (const float*)d_in[3];
    const float* w    = (const float*)d_in[4];
    const float* eps  = (const float*)d_in[5];
    const float* bias = (const float*)d_in[6];

    float* out = (float*)d_out;
    float* rep = out + (size_t)N_NODES * D;

    int* ws      = (int*)d_ws;
    int* ghist   = ws + WS_GHIST;
    int* partial = ws + WS_PART;
    int* row_ptr = ws + WS_ROWPTR;
    int* keys    = ws + WS_KEYS;
    int2* pairs  = (int2*)(ws + WS_PAIRS);
    int2* tpairs = (int2*)rep;   // consumed by k_build_csr before rep is written

    k_bucket_hist<<<BLKA, 256, 0, stream>>>(esrc, ghist);
    k_ghist_scan1<<<NCH, 1024, 0, stream>>>(ghist, partial);
    k_ghist_scan2<<<NCH, 1024, 0, stream>>>(ghist, partial);
    k_scatter<<<BLKA, 256, 0, stream>>>(esrc, edst, ev, ghist, keys, tpairs);
    k_build_csr<<<NB, 256, 0, stream>>>(keys, tpairs, ghist, row_ptr, pairs);
    k_gather<<<GATHER_BLOCKS, 256, 0, stream>>>(x, row_ptr, pairs, eps, rep);
    k_gemm<<<(N_NODES + GEMM_TM - 1) / GEMM_TM, 256, 0, stream>>>(rep, w, bias, out);
}